// Round 2
// baseline (46.354 us; speedup 1.0000x reference)
//
#include <hip/hip_runtime.h>
#include <hip/hip_bf16.h>

constexpr int NRES = 8192;
constexpr int NIN  = 64;
constexpr int NOUT = 32;
constexpr float DT_OVER_TAU = 0.1f / 10.0f;  // 0.01

typedef float float4v __attribute__((ext_vector_type(4)));

// One block per reservoir row:
//   state      = W[row,:]@r + W_in[row,:]@u + W_fb[row,:]@y
//   r_new[row] = r[row] + (dt/tau) * (tanh(state) - r[row])
__global__ __launch_bounds__(256) void reservoir_state_kernel(
    const float* __restrict__ W,
    const float* __restrict__ W_in,
    const float* __restrict__ W_fb,
    const float* __restrict__ u,
    const float* __restrict__ r,
    const float* __restrict__ y,
    float* __restrict__ r_new)
{
    const int row = blockIdx.x;
    const int t   = threadIdx.x;
    const float* wrow = W + (size_t)row * NRES;

    float acc = 0.0f;
#pragma unroll
    for (int j = 0; j < 8; ++j) {
        const int c = (j * 256 + t) * 4;              // 16B/lane, coalesced
        float4v wv = *reinterpret_cast<const float4v*>(wrow + c);
        float4v rv = *reinterpret_cast<const float4v*>(r + c);
        acc += wv[0] * rv[0] + wv[1] * rv[1] + wv[2] * rv[2] + wv[3] * rv[3];
    }
    // Tiny input/feedback dots, folded into the same block reduction.
    if (t < NIN)  acc += W_in[row * NIN + t] * u[t];
    if (t < NOUT) acc += W_fb[row * NOUT + t] * y[t];

    // wave(64) reduce, then LDS across the 4 waves
#pragma unroll
    for (int off = 32; off > 0; off >>= 1)
        acc += __shfl_down(acc, off, 64);

    __shared__ float partial[4];
    const int wid  = t >> 6;
    const int lane = t & 63;
    if (lane == 0) partial[wid] = acc;
    __syncthreads();

    if (t == 0) {
        float state = partial[0] + partial[1] + partial[2] + partial[3];
        float ri = r[row];
        r_new[row] = ri + DT_OVER_TAU * (tanhf(state) - ri);
    }
}

// One block per output row: out[o] = W_out[o,:] @ r_new
__global__ __launch_bounds__(256) void readout_kernel(
    const float* __restrict__ W_out,
    const float* __restrict__ r_new,
    float* __restrict__ out)
{
    const int row = blockIdx.x;   // 0..31
    const int t   = threadIdx.x;
    const float* wrow = W_out + (size_t)row * NRES;

    float acc = 0.0f;
#pragma unroll
    for (int j = 0; j < 8; ++j) {
        const int c = (j * 256 + t) * 4;
        float4v wv = *reinterpret_cast<const float4v*>(wrow + c);
        float4v rv = *reinterpret_cast<const float4v*>(r_new + c);
        acc += wv[0] * rv[0] + wv[1] * rv[1] + wv[2] * rv[2] + wv[3] * rv[3];
    }

#pragma unroll
    for (int off = 32; off > 0; off >>= 1)
        acc += __shfl_down(acc, off, 64);

    __shared__ float partial[4];
    const int wid  = t >> 6;
    const int lane = t & 63;
    if (lane == 0) partial[wid] = acc;
    __syncthreads();

    if (t == 0)
        out[row] = partial[0] + partial[1] + partial[2] + partial[3];
}

extern "C" void kernel_launch(void* const* d_in, const int* in_sizes, int n_in,
                              void* d_out, int out_size, void* d_ws, size_t ws_size,
                              hipStream_t stream) {
    // setup_inputs order: input_signal, W, W_in, W_fb, W_out, r, out_prev
    const float* u     = (const float*)d_in[0];
    const float* W     = (const float*)d_in[1];
    const float* W_in  = (const float*)d_in[2];
    const float* W_fb  = (const float*)d_in[3];
    const float* W_out = (const float*)d_in[4];
    const float* r     = (const float*)d_in[5];
    const float* y     = (const float*)d_in[6];

    float* r_new = (float*)d_ws;                 // 8192 floats = 32 KB scratch
    float* out   = (float*)d_out;

    reservoir_state_kernel<<<NRES, 256, 0, stream>>>(W, W_in, W_fb, u, r, y, r_new);
    readout_kernel<<<NOUT, 256, 0, stream>>>(W_out, r_new, out);
}